// Round 2
// baseline (867.911 us; speedup 1.0000x reference)
//
#include <hip/hip_runtime.h>
#include <math.h>

#define NTOK 8192
#define NE   16
#define CAP  640
#define EC   (NE * CAP)                       // 10240

constexpr size_t DISP_SZ  = (size_t)NTOK * EC;   // 83,886,080
constexpr size_t SCAL_OFF = 2 * DISP_SZ;         // 167,772,160
constexpr size_t LOG_OFF  = SCAL_OFF + 3;

// ws layout (bytes): key u64[8192] @0 ; pD double[2048*19] @65536 ; pI int[2048*16] @376832
#define WS_KEY 0
#define WS_PD  65536
#define WS_PI  376832

// ---------------------------------------------------------------------------
// K1: one token per wave. Lane l: expert e=l&15, channel-group g=l>>4
// (channels 16g..16g+15). f32-faithful math: f64 accumulate, round to f32 at
// every boundary numpy rounds (pooled, matmul out, /1.5, x-max, exp, sum, div)
// so the prob ordering matches the np-f32 reference to sub-ULP noise.
// ---------------------------------------------------------------------------
__global__ __launch_bounds__(256) void k_router(
    const float4* __restrict__ X4, const float* __restrict__ Wg,
    const float* __restrict__ bg, float* __restrict__ out,
    unsigned long long* __restrict__ key,
    double* __restrict__ pD, int* __restrict__ pI)
{
    __shared__ double sPex[4][NE];
    __shared__ float  sLog[4][NE];
    __shared__ double sLse[4];
    __shared__ int    sExp[4];

    const int tid = threadIdx.x;
    const int w   = tid >> 6;                 // wave = token slot
    const int l   = tid & 63;
    const int n   = blockIdx.x * 4 + w;
    const int e   = l & 15;                   // this lane's expert (and spatial quad)
    const int g   = l >> 4;                   // channel group

    float wreg[16];                           // Wg[16g+i][e] in registers
#pragma unroll
    for (int i = 0; i < 16; i++)
        wreg[i] = Wg[(16 * g + i) * 16 + e];

    const float4* xb = X4 + (size_t)n * 1024;
    double dot = 0.0;
#pragma unroll
    for (int i = 0; i < 16; i++) {
        // float4 idx 256g+16i+(l&15): channel c=16g+i, spatial quad j=l&15 -> coalesced
        float4 v = xb[g * 256 + i * 16 + e];
        double s4 = ((double)v.x + (double)v.y) + ((double)v.z + (double)v.w);
        s4 += __shfl_xor(s4, 1, 64);          // spatial sum across the 16-lane group
        s4 += __shfl_xor(s4, 2, 64);
        s4 += __shfl_xor(s4, 4, 64);
        s4 += __shfl_xor(s4, 8, 64);
        float pooled = (float)(s4 * (1.0 / 64.0));   // np: f32 mean (exact /64)
        dot += (double)pooled * (double)wreg[i];
    }
    dot += __shfl_xor(dot, 16, 64);           // sum the 4 channel groups
    dot += __shfl_xor(dot, 32, 64);

    float raw = (float)dot + bg[e];           // f32 matmul result, + bg (f32 add)
    float lg  = raw / 1.5f;                   // IEEE f32 division
    lg = fminf(fmaxf(lg, -10.0f), 10.0f);

    // argmax over experts (first-index tie-break), butterfly on lanes 0..15 pattern
    float mv = lg; int mi = e;
#pragma unroll
    for (int off = 1; off <= 8; off <<= 1) {
        float ov = __shfl_xor(mv, off, 64);
        int   oi = __shfl_xor(mi, off, 64);
        if (ov > mv || (ov == mv && oi < mi)) { mv = ov; mi = oi; }
    }

    float d  = lg - mv;                       // f32 subtract (exact rounding)
    float ex = (float)exp((double)d);         // correctly-rounded f32 exp
    double sd = (double)ex;
#pragma unroll
    for (int off = 1; off <= 8; off <<= 1)
        sd += __shfl_xor(sd, off, 64);        // sum of 16 exps
    float sumf = (float)sd;                   // round once (<=1.5 ULP vs np pairwise)
    float ptop = 1.0f / sumf;                 // f32 division, e_top == 1.0
    double lse = (double)mv + log(sd);

    // pack sort key: [46:43]=expert  [42:13]=prob f32 bits (<2^30)  [12:0]=8191-n
    unsigned int pb = __float_as_uint(ptop);
    unsigned long long kk = ((unsigned long long)mi << 43)
                          | ((unsigned long long)pb << 13)
                          | (unsigned long long)(8191 - n);

    if (l == 0) { key[n] = kk; sLse[w] = lse; sExp[w] = mi; }
    if (l < 16) {
        out[LOG_OFF + (size_t)n * 16 + e] = lg;
        sPex[w][e] = (double)ex / sd;
        sLog[w][e] = lg;
    }
    __syncthreads();

    if (tid < 16) {
        pD[blockIdx.x * 19 + 3 + tid] =
            sPex[0][tid] + sPex[1][tid] + sPex[2][tid] + sPex[3][tid];
        pI[blockIdx.x * 16 + tid] = (sExp[0] == tid) + (sExp[1] == tid)
                                  + (sExp[2] == tid) + (sExp[3] == tid);
    } else if (tid == 16) {
        double z = 0.0;
        for (int i = 0; i < 4; i++) z += sLse[i] * sLse[i];
        pD[blockIdx.x * 19 + 0] = z;
    } else if (tid == 17) {
        double s = 0.0;
        for (int i = 0; i < 4; i++)
            for (int j = 0; j < 16; j++) s += (double)sLog[i][j];
        pD[blockIdx.x * 19 + 1] = s;
    } else if (tid == 18) {
        double s = 0.0;
        for (int i = 0; i < 4; i++)
            for (int j = 0; j < 16; j++) {
                double v = (double)sLog[i][j]; s += v * v;
            }
        pD[blockIdx.x * 19 + 2] = s;
    }
}

// ---------------------------------------------------------------------------
// K2: rank token among same-expert tokens by (prob desc, idx asc) = count of
// keys with same expert field and larger packed key. 32 lanes scan per token;
// keys (64 KB) are L2-resident.
// ---------------------------------------------------------------------------
__global__ __launch_bounds__(256) void k_rank(
    const unsigned long long* __restrict__ key, float* __restrict__ out)
{
    const int tid = threadIdx.x;
    const int tok = blockIdx.x * 8 + (tid >> 5);
    const int sub = tid & 31;
    const unsigned long long me = key[tok];
    const unsigned long long my_e = me >> 43;

    int cnt = 0;
    for (int m = sub; m < NTOK; m += 32) {
        unsigned long long km = key[m];
        cnt += ((km >> 43) == my_e && km > me) ? 1 : 0;
    }
#pragma unroll
    for (int off = 16; off >= 1; off >>= 1)
        cnt += __shfl_down(cnt, off, 32);

    if (sub == 0 && cnt < CAP) {
        size_t idx = (size_t)tok * EC + (size_t)my_e * CAP + (size_t)cnt;
        out[idx] = 1.0f;              // dispatch
        out[DISP_SZ + idx] = 1.0f;    // combine (w == 1.0 exactly for top-1)
    }
}

// ---------------------------------------------------------------------------
// K3: reduce 2048 partial rows -> z_loss, aux_loss, logits_std.
// ---------------------------------------------------------------------------
__global__ __launch_bounds__(256) void k_finalize(
    const double* __restrict__ pD, const int* __restrict__ pI,
    float* __restrict__ out)
{
    __shared__ double red[256];
    __shared__ double tot[19];
    __shared__ int    totI[NE];
    const int t = threadIdx.x;

    for (int f = 0; f < 19; f++) {
        double s = 0.0;
        for (int b = t; b < 2048; b += 256) s += pD[b * 19 + f];
        red[t] = s; __syncthreads();
        for (int off = 128; off >= 1; off >>= 1) {
            if (t < off) red[t] += red[t + off];
            __syncthreads();
        }
        if (t == 0) tot[f] = red[0];
        __syncthreads();
    }
    for (int f = 0; f < NE; f++) {
        int s = 0;
        for (int b = t; b < 2048; b += 256) s += pI[b * 16 + f];
        red[t] = (double)s; __syncthreads();
        for (int off = 128; off >= 1; off >>= 1) {
            if (t < off) red[t] += red[t + off];
            __syncthreads();
        }
        if (t == 0) totI[f] = (int)(red[0] + 0.5);
        __syncthreads();
    }

    if (t == 0) {
        double z = tot[0] / (double)NTOK;
        double aux = 0.0;
        for (int e = 0; e < NE; e++) {
            int kept = totI[e] < CAP ? totI[e] : CAP;
            aux += ((double)kept / (double)NTOK) * (tot[3 + e] / (double)NTOK);
        }
        aux *= (double)NE;
        double cntall = (double)NTOK * NE;
        double mean = tot[1] / cntall;
        double var  = tot[2] / cntall - mean * mean;
        if (var < 0.0) var = 0.0;
        out[SCAL_OFF + 0] = (float)z;
        out[SCAL_OFF + 1] = (float)aux;
        out[SCAL_OFF + 2] = (float)sqrt(var);
    }
}

extern "C" void kernel_launch(void* const* d_in, const int* in_sizes, int n_in,
                              void* d_out, int out_size, void* d_ws, size_t ws_size,
                              hipStream_t stream)
{
    const float* X  = (const float*)d_in[0];
    const float* Wg = (const float*)d_in[1];
    const float* bg = (const float*)d_in[2];
    float* out = (float*)d_out;

    char* ws = (char*)d_ws;
    unsigned long long* key = (unsigned long long*)(ws + WS_KEY);
    double* pD = (double*)(ws + WS_PD);
    int*    pI = (int*)   (ws + WS_PI);

    hipMemsetAsync(d_out, 0, (size_t)out_size * sizeof(float), stream);

    k_router<<<NTOK / 4, 256, 0, stream>>>((const float4*)X, Wg, bg, out,
                                           key, pD, pI);
    k_rank<<<NTOK / 8, 256, 0, stream>>>(key, out);
    k_finalize<<<1, 256, 0, stream>>>(pD, pI, out);
}

// Round 3
// 843.541 us; speedup vs baseline: 1.0289x; 1.0289x over previous
//
#include <hip/hip_runtime.h>
#include <math.h>

#define NTOK 8192
#define NE   16
#define CAP  640
#define EC   (NE * CAP)                       // 10240

constexpr size_t DISP_SZ  = (size_t)NTOK * EC;   // 83,886,080
constexpr size_t SCAL_OFF = 2 * DISP_SZ;         // 167,772,160
constexpr size_t LOG_OFF  = SCAL_OFF + 3;

// ws layout (bytes): key u64[8192] @0 ; pD double[2048*19] @65536 ; pI int[2048*16] @376832
#define WS_KEY 0
#define WS_PD  65536
#define WS_PI  376832

// ---------------------------------------------------------------------------
// K1: one token per wave. Lane l: expert e=l&15, channel-group g=l>>4
// (channels 16g..16g+15). f32-faithful math: f64 accumulate, round to f32 at
// every boundary numpy rounds (pooled, matmul out, /1.5, x-max, exp, sum, div)
// so the prob ordering matches the np-f32 reference to sub-ULP noise.
// PASSED R2 bit-exactly on dispatch ordering — numerics frozen, do not touch.
// ---------------------------------------------------------------------------
__global__ __launch_bounds__(256) void k_router(
    const float4* __restrict__ X4, const float* __restrict__ Wg,
    const float* __restrict__ bg, float* __restrict__ out,
    unsigned long long* __restrict__ key,
    double* __restrict__ pD, int* __restrict__ pI)
{
    __shared__ double sPex[4][NE];
    __shared__ float  sLog[4][NE];
    __shared__ double sLse[4];
    __shared__ int    sExp[4];

    const int tid = threadIdx.x;
    const int w   = tid >> 6;                 // wave = token slot
    const int l   = tid & 63;
    const int n   = blockIdx.x * 4 + w;
    const int e   = l & 15;                   // this lane's expert (and spatial quad)
    const int g   = l >> 4;                   // channel group

    float wreg[16];                           // Wg[16g+i][e] in registers
#pragma unroll
    for (int i = 0; i < 16; i++)
        wreg[i] = Wg[(16 * g + i) * 16 + e];

    const float4* xb = X4 + (size_t)n * 1024;
    double dot = 0.0;
#pragma unroll
    for (int i = 0; i < 16; i++) {
        float4 v = xb[g * 256 + i * 16 + e];
        double s4 = ((double)v.x + (double)v.y) + ((double)v.z + (double)v.w);
        s4 += __shfl_xor(s4, 1, 64);          // spatial sum across the 16-lane group
        s4 += __shfl_xor(s4, 2, 64);
        s4 += __shfl_xor(s4, 4, 64);
        s4 += __shfl_xor(s4, 8, 64);
        float pooled = (float)(s4 * (1.0 / 64.0));   // np: f32 mean (exact /64)
        dot += (double)pooled * (double)wreg[i];
    }
    dot += __shfl_xor(dot, 16, 64);           // sum the 4 channel groups
    dot += __shfl_xor(dot, 32, 64);

    float raw = (float)dot + bg[e];           // f32 matmul result, + bg (f32 add)
    float lg  = raw / 1.5f;                   // IEEE f32 division
    lg = fminf(fmaxf(lg, -10.0f), 10.0f);

    // argmax over experts (first-index tie-break)
    float mv = lg; int mi = e;
#pragma unroll
    for (int off = 1; off <= 8; off <<= 1) {
        float ov = __shfl_xor(mv, off, 64);
        int   oi = __shfl_xor(mi, off, 64);
        if (ov > mv || (ov == mv && oi < mi)) { mv = ov; mi = oi; }
    }

    float d  = lg - mv;                       // f32 subtract
    float ex = (float)exp((double)d);         // correctly-rounded f32 exp
    double sd = (double)ex;
#pragma unroll
    for (int off = 1; off <= 8; off <<= 1)
        sd += __shfl_xor(sd, off, 64);        // sum of 16 exps
    float sumf = (float)sd;
    float ptop = 1.0f / sumf;
    double lse = (double)mv + log(sd);

    // pack sort key: [46:43]=expert  [42:13]=prob f32 bits  [12:0]=8191-n
    unsigned int pb = __float_as_uint(ptop);
    unsigned long long kk = ((unsigned long long)mi << 43)
                          | ((unsigned long long)pb << 13)
                          | (unsigned long long)(8191 - n);

    if (l == 0) { key[n] = kk; sLse[w] = lse; sExp[w] = mi; }
    if (l < 16) {
        out[LOG_OFF + (size_t)n * 16 + e] = lg;
        sPex[w][e] = (double)ex / sd;
        sLog[w][e] = lg;
    }
    __syncthreads();

    if (tid < 16) {
        pD[blockIdx.x * 19 + 3 + tid] =
            sPex[0][tid] + sPex[1][tid] + sPex[2][tid] + sPex[3][tid];
        pI[blockIdx.x * 16 + tid] = (sExp[0] == tid) + (sExp[1] == tid)
                                  + (sExp[2] == tid) + (sExp[3] == tid);
    } else if (tid == 16) {
        double z = 0.0;
        for (int i = 0; i < 4; i++) z += sLse[i] * sLse[i];
        pD[blockIdx.x * 19 + 0] = z;
    } else if (tid == 17) {
        double s = 0.0;
        for (int i = 0; i < 4; i++)
            for (int j = 0; j < 16; j++) s += (double)sLog[i][j];
        pD[blockIdx.x * 19 + 1] = s;
    } else if (tid == 18) {
        double s = 0.0;
        for (int i = 0; i < 4; i++)
            for (int j = 0; j < 16; j++) {
                double v = (double)sLog[i][j]; s += v * v;
            }
        pD[blockIdx.x * 19 + 2] = s;
    }
}

// ---------------------------------------------------------------------------
// K2: rank token among same-expert tokens by (prob desc, idx asc) = count of
// keys with same expert field and larger packed key. 32 lanes scan per token;
// keys (64 KB) are L2-resident.
// ---------------------------------------------------------------------------
__global__ __launch_bounds__(256) void k_rank(
    const unsigned long long* __restrict__ key, float* __restrict__ out)
{
    const int tid = threadIdx.x;
    const int tok = blockIdx.x * 8 + (tid >> 5);
    const int sub = tid & 31;
    const unsigned long long me = key[tok];
    const unsigned long long my_e = me >> 43;

    int cnt = 0;
    for (int m = sub; m < NTOK; m += 32) {
        unsigned long long km = key[m];
        cnt += ((km >> 43) == my_e && km > me) ? 1 : 0;
    }
#pragma unroll
    for (int off = 16; off >= 1; off >>= 1)
        cnt += __shfl_down(cnt, off, 32);

    if (sub == 0 && cnt < CAP) {
        size_t idx = (size_t)tok * EC + (size_t)my_e * CAP + (size_t)cnt;
        out[idx] = 1.0f;              // dispatch
        out[DISP_SZ + idx] = 1.0f;    // combine (w == 1.0 exactly for top-1)
    }
}

// ---------------------------------------------------------------------------
// K3: reduce 2048 partial rows -> z_loss, aux_loss, logits_std.
// Rewritten: per-thread strided accumulation over 8 rows (all fields in
// registers), one LDS dump, 2 barriers total (was ~280 barrier rounds).
// ---------------------------------------------------------------------------
__global__ __launch_bounds__(256) void k_finalize(
    const double* __restrict__ pD, const int* __restrict__ pI,
    float* __restrict__ out)
{
    __shared__ double sD[256][20];    // 19 fields, pad to 20 (40 KB)
    __shared__ int    sI[256][NE];    // 16 KB
    const int t = threadIdx.x;

    double a[19];
#pragma unroll
    for (int f = 0; f < 19; f++) a[f] = 0.0;
    int ci[NE];
#pragma unroll
    for (int f = 0; f < NE; f++) ci[f] = 0;

    for (int b = t; b < 2048; b += 256) {
        const double* rowD = pD + b * 19;
#pragma unroll
        for (int f = 0; f < 19; f++) a[f] += rowD[f];
        const int* rowI = pI + b * NE;
#pragma unroll
        for (int f = 0; f < NE; f++) ci[f] += rowI[f];
    }
#pragma unroll
    for (int f = 0; f < 19; f++) sD[t][f] = a[f];
#pragma unroll
    for (int f = 0; f < NE; f++) sI[t][f] = ci[f];
    __syncthreads();

    if (t == 0) {
        double tot[19];
        for (int f = 0; f < 19; f++) tot[f] = 0.0;
        int totI[NE];
        for (int f = 0; f < NE; f++) totI[f] = 0;
        for (int i = 0; i < 256; i++) {
            for (int f = 0; f < 19; f++) tot[f] += sD[i][f];
            for (int f = 0; f < NE; f++) totI[f] += sI[i][f];
        }
        double z = tot[0] / (double)NTOK;
        double aux = 0.0;
        for (int e = 0; e < NE; e++) {
            int kept = totI[e] < CAP ? totI[e] : CAP;
            aux += ((double)kept / (double)NTOK) * (tot[3 + e] / (double)NTOK);
        }
        aux *= (double)NE;
        double cntall = (double)NTOK * NE;
        double mean = tot[1] / cntall;
        double var  = tot[2] / cntall - mean * mean;
        if (var < 0.0) var = 0.0;
        out[SCAL_OFF + 0] = (float)z;
        out[SCAL_OFF + 1] = (float)aux;
        out[SCAL_OFF + 2] = (float)sqrt(var);
    }
}

extern "C" void kernel_launch(void* const* d_in, const int* in_sizes, int n_in,
                              void* d_out, int out_size, void* d_ws, size_t ws_size,
                              hipStream_t stream)
{
    const float* X  = (const float*)d_in[0];
    const float* Wg = (const float*)d_in[1];
    const float* bg = (const float*)d_in[2];
    float* out = (float*)d_out;

    char* ws = (char*)d_ws;
    unsigned long long* key = (unsigned long long*)(ws + WS_KEY);
    double* pD = (double*)(ws + WS_PD);
    int*    pI = (int*)   (ws + WS_PI);

    hipMemsetAsync(d_out, 0, (size_t)out_size * sizeof(float), stream);

    k_router<<<NTOK / 4, 256, 0, stream>>>((const float4*)X, Wg, bg, out,
                                           key, pD, pI);
    k_rank<<<NTOK / 8, 256, 0, stream>>>(key, out);
    k_finalize<<<1, 256, 0, stream>>>(pD, pI, out);
}

// Round 4
// 823.254 us; speedup vs baseline: 1.0542x; 1.0246x over previous
//
#include <hip/hip_runtime.h>
#include <math.h>

#define NTOK 8192
#define NE   16
#define CAP  640
#define EC   (NE * CAP)                       // 10240

constexpr size_t DISP_SZ  = (size_t)NTOK * EC;   // 83,886,080
constexpr size_t SCAL_OFF = 2 * DISP_SZ;         // 167,772,160
constexpr size_t LOG_OFF  = SCAL_OFF + 3;

// ws layout (bytes): key u64[8192] @0 ; pD double[2048*19] @65536 ; pI int[2048*16] @376832
#define WS_KEY 0
#define WS_PD  65536
#define WS_PI  376832

#define NZBLK 10240        // zero blocks: each writes 4096 float4 = 64 KB
#define NRBLK 2048         // router blocks: 4 tokens each

// ---------------------------------------------------------------------------
// K_MAIN: blockIdx < NRBLK -> router (numerics FROZEN, bit-exact vs np-f32
// ordering, passed R2/R3); blockIdx >= NRBLK -> zero a 64 KB chunk of the
// dispatch+combine region. Logits are fully written by router blocks and the
// 3 scalars by the finalize block, so only [0, 2*DISP_SZ) needs zeroing.
// One launch => zero-writes and X-reads share the HBM window.
// ---------------------------------------------------------------------------
__global__ __launch_bounds__(256) void k_main(
    const float4* __restrict__ X4, const float* __restrict__ Wg,
    const float* __restrict__ bg, float* __restrict__ out,
    unsigned long long* __restrict__ key,
    double* __restrict__ pD, int* __restrict__ pI)
{
    const int tid = threadIdx.x;

    if (blockIdx.x >= NRBLK) {
        // ---- zero path: 4096 float4 per block, coalesced stride-256 ----
        float4* o4 = (float4*)out + (size_t)(blockIdx.x - NRBLK) * 4096;
        const float4 z = make_float4(0.f, 0.f, 0.f, 0.f);
#pragma unroll
        for (int k = 0; k < 16; k++)
            o4[tid + 256 * k] = z;
        return;
    }

    // ---- router path (frozen) ----
    __shared__ double sPex[4][NE];
    __shared__ float  sLog[4][NE];
    __shared__ double sLse[4];
    __shared__ int    sExp[4];

    const int w   = tid >> 6;                 // wave = token slot
    const int l   = tid & 63;
    const int n   = blockIdx.x * 4 + w;
    const int e   = l & 15;                   // this lane's expert (and spatial quad)
    const int g   = l >> 4;                   // channel group

    float wreg[16];                           // Wg[16g+i][e] in registers
#pragma unroll
    for (int i = 0; i < 16; i++)
        wreg[i] = Wg[(16 * g + i) * 16 + e];

    const float4* xb = X4 + (size_t)n * 1024;
    double dot = 0.0;
#pragma unroll
    for (int i = 0; i < 16; i++) {
        float4 v = xb[g * 256 + i * 16 + e];
        double s4 = ((double)v.x + (double)v.y) + ((double)v.z + (double)v.w);
        s4 += __shfl_xor(s4, 1, 64);          // spatial sum across the 16-lane group
        s4 += __shfl_xor(s4, 2, 64);
        s4 += __shfl_xor(s4, 4, 64);
        s4 += __shfl_xor(s4, 8, 64);
        float pooled = (float)(s4 * (1.0 / 64.0));   // np: f32 mean (exact /64)
        dot += (double)pooled * (double)wreg[i];
    }
    dot += __shfl_xor(dot, 16, 64);           // sum the 4 channel groups
    dot += __shfl_xor(dot, 32, 64);

    float raw = (float)dot + bg[e];           // f32 matmul result, + bg (f32 add)
    float lg  = raw / 1.5f;                   // IEEE f32 division
    lg = fminf(fmaxf(lg, -10.0f), 10.0f);

    // argmax over experts (first-index tie-break)
    float mv = lg; int mi = e;
#pragma unroll
    for (int off = 1; off <= 8; off <<= 1) {
        float ov = __shfl_xor(mv, off, 64);
        int   oi = __shfl_xor(mi, off, 64);
        if (ov > mv || (ov == mv && oi < mi)) { mv = ov; mi = oi; }
    }

    float d  = lg - mv;                       // f32 subtract
    float ex = (float)exp((double)d);         // correctly-rounded f32 exp
    double sd = (double)ex;
#pragma unroll
    for (int off = 1; off <= 8; off <<= 1)
        sd += __shfl_xor(sd, off, 64);        // sum of 16 exps
    float sumf = (float)sd;
    float ptop = 1.0f / sumf;
    double lse = (double)mv + log(sd);

    // pack sort key: [46:43]=expert  [42:13]=prob f32 bits  [12:0]=8191-n
    unsigned int pb = __float_as_uint(ptop);
    unsigned long long kk = ((unsigned long long)mi << 43)
                          | ((unsigned long long)pb << 13)
                          | (unsigned long long)(8191 - n);

    if (l == 0) { key[n] = kk; sLse[w] = lse; sExp[w] = mi; }
    if (l < 16) {
        out[LOG_OFF + (size_t)n * 16 + e] = lg;
        sPex[w][e] = (double)ex / sd;
        sLog[w][e] = lg;
    }
    __syncthreads();

    if (tid < 16) {
        pD[blockIdx.x * 19 + 3 + tid] =
            sPex[0][tid] + sPex[1][tid] + sPex[2][tid] + sPex[3][tid];
        pI[blockIdx.x * 16 + tid] = (sExp[0] == tid) + (sExp[1] == tid)
                                  + (sExp[2] == tid) + (sExp[3] == tid);
    } else if (tid == 16) {
        double z = 0.0;
        for (int i = 0; i < 4; i++) z += sLse[i] * sLse[i];
        pD[blockIdx.x * 19 + 0] = z;
    } else if (tid == 17) {
        double s = 0.0;
        for (int i = 0; i < 4; i++)
            for (int j = 0; j < 16; j++) s += (double)sLog[i][j];
        pD[blockIdx.x * 19 + 1] = s;
    } else if (tid == 18) {
        double s = 0.0;
        for (int i = 0; i < 4; i++)
            for (int j = 0; j < 16; j++) {
                double v = (double)sLog[i][j]; s += v * v;
            }
        pD[blockIdx.x * 19 + 2] = s;
    }
}

// ---------------------------------------------------------------------------
// K_SCATTER: blockIdx < 1024 -> rank+scatter with keys staged in LDS (cuts
// L2 key traffic 512 MB -> 64 MB); blockIdx == 1024 -> finalize reductions.
// ---------------------------------------------------------------------------
__global__ __launch_bounds__(256) void k_scatter(
    const unsigned long long* __restrict__ key,
    const double* __restrict__ pD, const int* __restrict__ pI,
    float* __restrict__ out)
{
    __shared__ unsigned long long skey[NTOK];   // 64 KB (aliased by finalize)
    const int tid = threadIdx.x;

    if (blockIdx.x < 1024) {
        // stage all 8192 keys: each thread loads 32, coalesced
        for (int k = 0; k < 32; k++)
            skey[tid + 256 * k] = key[tid + 256 * k];
        __syncthreads();

        const int tok = blockIdx.x * 8 + (tid >> 5);
        const int sub = tid & 31;
        const unsigned long long me = skey[tok];
        const unsigned long long my_e = me >> 43;

        int cnt = 0;
        // lane s reads skey[s+32t]: 32 distinct u64 -> 2-way bank alias (free),
        // 2-way same-address broadcast across the two token-halves of the wave
        for (int m = sub; m < NTOK; m += 32) {
            unsigned long long km = skey[m];
            cnt += ((km >> 43) == my_e && km > me) ? 1 : 0;
        }
#pragma unroll
        for (int off = 16; off >= 1; off >>= 1)
            cnt += __shfl_down(cnt, off, 32);

        if (sub == 0 && cnt < CAP) {
            size_t idx = (size_t)tok * EC + (size_t)my_e * CAP + (size_t)cnt;
            out[idx] = 1.0f;              // dispatch
            out[DISP_SZ + idx] = 1.0f;    // combine (w == 1.0 exactly, top-1)
        }
        return;
    }

    // ---- finalize path (one block): reduce 2048 partial rows ----
    double* sD = (double*)skey;               // [256][20] = 40960 B
    int*    sI = (int*)(skey + 5120);         // [256][16] = 16384 B
    double a[19];
#pragma unroll
    for (int f = 0; f < 19; f++) a[f] = 0.0;
    int ci[NE];
#pragma unroll
    for (int f = 0; f < NE; f++) ci[f] = 0;

    for (int b = tid; b < 2048; b += 256) {
        const double* rowD = pD + b * 19;
#pragma unroll
        for (int f = 0; f < 19; f++) a[f] += rowD[f];
        const int* rowI = pI + b * NE;
#pragma unroll
        for (int f = 0; f < NE; f++) ci[f] += rowI[f];
    }
#pragma unroll
    for (int f = 0; f < 19; f++) sD[tid * 20 + f] = a[f];
#pragma unroll
    for (int f = 0; f < NE; f++) sI[tid * 16 + f] = ci[f];
    __syncthreads();

    if (tid == 0) {
        double tot[19];
        for (int f = 0; f < 19; f++) tot[f] = 0.0;
        int totI[NE];
        for (int f = 0; f < NE; f++) totI[f] = 0;
        for (int i = 0; i < 256; i++) {
            for (int f = 0; f < 19; f++) tot[f] += sD[i * 20 + f];
            for (int f = 0; f < NE; f++) totI[f] += sI[i * 16 + f];
        }
        double z = tot[0] / (double)NTOK;
        double aux = 0.0;
        for (int e = 0; e < NE; e++) {
            int kept = totI[e] < CAP ? totI[e] : CAP;
            aux += ((double)kept / (double)NTOK) * (tot[3 + e] / (double)NTOK);
        }
        aux *= (double)NE;
        double cntall = (double)NTOK * NE;
        double mean = tot[1] / cntall;
        double var  = tot[2] / cntall - mean * mean;
        if (var < 0.0) var = 0.0;
        out[SCAL_OFF + 0] = (float)z;
        out[SCAL_OFF + 1] = (float)aux;
        out[SCAL_OFF + 2] = (float)sqrt(var);
    }
}

extern "C" void kernel_launch(void* const* d_in, const int* in_sizes, int n_in,
                              void* d_out, int out_size, void* d_ws, size_t ws_size,
                              hipStream_t stream)
{
    const float* X  = (const float*)d_in[0];
    const float* Wg = (const float*)d_in[1];
    const float* bg = (const float*)d_in[2];
    float* out = (float*)d_out;

    char* ws = (char*)d_ws;
    unsigned long long* key = (unsigned long long*)(ws + WS_KEY);
    double* pD = (double*)(ws + WS_PD);
    int*    pI = (int*)   (ws + WS_PI);

    k_main<<<NRBLK + NZBLK, 256, 0, stream>>>((const float4*)X, Wg, bg, out,
                                              key, pD, pI);
    k_scatter<<<1025, 256, 0, stream>>>(key, pD, pI, out);
}

// Round 6
// 821.224 us; speedup vs baseline: 1.0569x; 1.0025x over previous
//
#include <hip/hip_runtime.h>
#include <math.h>

#define NTOK 8192
#define NE   16
#define CAP  640
#define EC   (NE * CAP)                       // 10240

constexpr size_t DISP_SZ  = (size_t)NTOK * EC;   // 83,886,080
constexpr size_t SCAL_OFF = 2 * DISP_SZ;         // 167,772,160
constexpr size_t LOG_OFF  = SCAL_OFF + 3;

// ws layout (bytes): key u64[8192] @0 ; pD double[2048*19] @65536 ; pI int[2048*16] @376832
#define WS_KEY 0
#define WS_PD  65536
#define WS_PI  376832

#define NZBLK 5120         // zero blocks: each writes 8192 float4 = 128 KB
#define NRBLK 2048         // router blocks: 4 tokens each

typedef float vf4 __attribute__((ext_vector_type(4)));   // native vec for NT store

// ---------------------------------------------------------------------------
// K_MAIN: blockIdx < NRBLK -> router (numerics FROZEN — bit-exact vs np-f32
// ordering, passed R2/R3/R4); blockIdx >= NRBLK -> zero a 128 KB chunk of the
// dispatch+combine region with NONTEMPORAL stores (bypass L2 write-allocate so
// the 671 MB zero stream doesn't evict the X lines router blocks are reading).
// ---------------------------------------------------------------------------
__global__ __launch_bounds__(256) void k_main(
    const float4* __restrict__ X4, const float* __restrict__ Wg,
    const float* __restrict__ bg, float* __restrict__ out,
    unsigned long long* __restrict__ key,
    double* __restrict__ pD, int* __restrict__ pI)
{
    const int tid = threadIdx.x;

    if (blockIdx.x >= NRBLK) {
        // ---- zero path: 8192 float4 per block, coalesced, L2-bypass ----
        vf4* o4 = (vf4*)out + (size_t)(blockIdx.x - NRBLK) * 8192;
        const vf4 z = {0.f, 0.f, 0.f, 0.f};
#pragma unroll
        for (int k = 0; k < 32; k++)
            __builtin_nontemporal_store(z, o4 + tid + 256 * k);
        return;
    }

    // ---- router path (frozen) ----
    __shared__ double sPex[4][NE];
    __shared__ float  sLog[4][NE];
    __shared__ double sLse[4];
    __shared__ int    sExp[4];

    const int w   = tid >> 6;                 // wave = token slot
    const int l   = tid & 63;
    const int n   = blockIdx.x * 4 + w;
    const int e   = l & 15;                   // this lane's expert (and spatial quad)
    const int g   = l >> 4;                   // channel group

    float wreg[16];                           // Wg[16g+i][e] in registers
#pragma unroll
    for (int i = 0; i < 16; i++)
        wreg[i] = Wg[(16 * g + i) * 16 + e];

    const float4* xb = X4 + (size_t)n * 1024;
    double dot = 0.0;
#pragma unroll
    for (int i = 0; i < 16; i++) {
        float4 v = xb[g * 256 + i * 16 + e];
        double s4 = ((double)v.x + (double)v.y) + ((double)v.z + (double)v.w);
        s4 += __shfl_xor(s4, 1, 64);          // spatial sum across the 16-lane group
        s4 += __shfl_xor(s4, 2, 64);
        s4 += __shfl_xor(s4, 4, 64);
        s4 += __shfl_xor(s4, 8, 64);
        float pooled = (float)(s4 * (1.0 / 64.0));   // np: f32 mean (exact /64)
        dot += (double)pooled * (double)wreg[i];
    }
    dot += __shfl_xor(dot, 16, 64);           // sum the 4 channel groups
    dot += __shfl_xor(dot, 32, 64);

    float raw = (float)dot + bg[e];           // f32 matmul result, + bg (f32 add)
    float lg  = raw / 1.5f;                   // IEEE f32 division
    lg = fminf(fmaxf(lg, -10.0f), 10.0f);

    // argmax over experts (first-index tie-break)
    float mv = lg; int mi = e;
#pragma unroll
    for (int off = 1; off <= 8; off <<= 1) {
        float ov = __shfl_xor(mv, off, 64);
        int   oi = __shfl_xor(mi, off, 64);
        if (ov > mv || (ov == mv && oi < mi)) { mv = ov; mi = oi; }
    }

    float d  = lg - mv;                       // f32 subtract
    float ex = (float)exp((double)d);         // correctly-rounded f32 exp
    double sd = (double)ex;
#pragma unroll
    for (int off = 1; off <= 8; off <<= 1)
        sd += __shfl_xor(sd, off, 64);        // sum of 16 exps
    float sumf = (float)sd;
    float ptop = 1.0f / sumf;
    double lse = (double)mv + log(sd);

    // pack sort key: [46:43]=expert  [42:13]=prob f32 bits  [12:0]=8191-n
    unsigned int pb = __float_as_uint(ptop);
    unsigned long long kk = ((unsigned long long)mi << 43)
                          | ((unsigned long long)pb << 13)
                          | (unsigned long long)(8191 - n);

    if (l == 0) { key[n] = kk; sLse[w] = lse; sExp[w] = mi; }
    if (l < 16) {
        out[LOG_OFF + (size_t)n * 16 + e] = lg;
        sPex[w][e] = (double)ex / sd;
        sLog[w][e] = lg;
    }
    __syncthreads();

    if (tid < 16) {
        pD[blockIdx.x * 19 + 3 + tid] =
            sPex[0][tid] + sPex[1][tid] + sPex[2][tid] + sPex[3][tid];
        pI[blockIdx.x * 16 + tid] = (sExp[0] == tid) + (sExp[1] == tid)
                                  + (sExp[2] == tid) + (sExp[3] == tid);
    } else if (tid == 16) {
        double z = 0.0;
        for (int i = 0; i < 4; i++) z += sLse[i] * sLse[i];
        pD[blockIdx.x * 19 + 0] = z;
    } else if (tid == 17) {
        double s = 0.0;
        for (int i = 0; i < 4; i++)
            for (int j = 0; j < 16; j++) s += (double)sLog[i][j];
        pD[blockIdx.x * 19 + 1] = s;
    } else if (tid == 18) {
        double s = 0.0;
        for (int i = 0; i < 4; i++)
            for (int j = 0; j < 16; j++) {
                double v = (double)sLog[i][j]; s += v * v;
            }
        pD[blockIdx.x * 19 + 2] = s;
    }
}

// ---------------------------------------------------------------------------
// K_SCATTER: blockIdx < 1024 -> rank+scatter with keys staged in LDS;
// blockIdx == 1024 -> finalize reductions.
// ---------------------------------------------------------------------------
__global__ __launch_bounds__(256) void k_scatter(
    const unsigned long long* __restrict__ key,
    const double* __restrict__ pD, const int* __restrict__ pI,
    float* __restrict__ out)
{
    __shared__ unsigned long long skey[NTOK];   // 64 KB (aliased by finalize)
    const int tid = threadIdx.x;

    if (blockIdx.x < 1024) {
        for (int k = 0; k < 32; k++)
            skey[tid + 256 * k] = key[tid + 256 * k];
        __syncthreads();

        const int tok = blockIdx.x * 8 + (tid >> 5);
        const int sub = tid & 31;
        const unsigned long long me = skey[tok];
        const unsigned long long my_e = me >> 43;

        int cnt = 0;
        for (int m = sub; m < NTOK; m += 32) {
            unsigned long long km = skey[m];
            cnt += ((km >> 43) == my_e && km > me) ? 1 : 0;
        }
#pragma unroll
        for (int off = 16; off >= 1; off >>= 1)
            cnt += __shfl_down(cnt, off, 32);

        if (sub == 0 && cnt < CAP) {
            size_t idx = (size_t)tok * EC + (size_t)my_e * CAP + (size_t)cnt;
            __builtin_nontemporal_store(1.0f, out + idx);            // dispatch
            __builtin_nontemporal_store(1.0f, out + DISP_SZ + idx);  // combine
        }
        return;
    }

    // ---- finalize path (one block): reduce 2048 partial rows ----
    double* sD = (double*)skey;               // [256][20] = 40960 B
    int*    sI = (int*)(skey + 5120);         // [256][16] = 16384 B
    double a[19];
#pragma unroll
    for (int f = 0; f < 19; f++) a[f] = 0.0;
    int ci[NE];
#pragma unroll
    for (int f = 0; f < NE; f++) ci[f] = 0;

    for (int b = tid; b < 2048; b += 256) {
        const double* rowD = pD + b * 19;
#pragma unroll
        for (int f = 0; f < 19; f++) a[f] += rowD[f];
        const int* rowI = pI + b * NE;
#pragma unroll
        for (int f = 0; f < NE; f++) ci[f] += rowI[f];
    }
#pragma unroll
    for (int f = 0; f < 19; f++) sD[tid * 20 + f] = a[f];
#pragma unroll
    for (int f = 0; f < NE; f++) sI[tid * 16 + f] = ci[f];
    __syncthreads();

    if (tid == 0) {
        double tot[19];
        for (int f = 0; f < 19; f++) tot[f] = 0.0;
        int totI[NE];
        for (int f = 0; f < NE; f++) totI[f] = 0;
        for (int i = 0; i < 256; i++) {
            for (int f = 0; f < 19; f++) tot[f] += sD[i * 20 + f];
            for (int f = 0; f < NE; f++) totI[f] += sI[i * 16 + f];
        }
        double z = tot[0] / (double)NTOK;
        double aux = 0.0;
        for (int e = 0; e < NE; e++) {
            int kept = totI[e] < CAP ? totI[e] : CAP;
            aux += ((double)kept / (double)NTOK) * (tot[3 + e] / (double)NTOK);
        }
        aux *= (double)NE;
        double cntall = (double)NTOK * NE;
        double mean = tot[1] / cntall;
        double var  = tot[2] / cntall - mean * mean;
        if (var < 0.0) var = 0.0;
        out[SCAL_OFF + 0] = (float)z;
        out[SCAL_OFF + 1] = (float)aux;
        out[SCAL_OFF + 2] = (float)sqrt(var);
    }
}

extern "C" void kernel_launch(void* const* d_in, const int* in_sizes, int n_in,
                              void* d_out, int out_size, void* d_ws, size_t ws_size,
                              hipStream_t stream)
{
    const float* X  = (const float*)d_in[0];
    const float* Wg = (const float*)d_in[1];
    const float* bg = (const float*)d_in[2];
    float* out = (float*)d_out;

    char* ws = (char*)d_ws;
    unsigned long long* key = (unsigned long long*)(ws + WS_KEY);
    double* pD = (double*)(ws + WS_PD);
    int*    pI = (int*)   (ws + WS_PI);

    k_main<<<NRBLK + NZBLK, 256, 0, stream>>>((const float4*)X, Wg, bg, out,
                                              key, pD, pI);
    k_scatter<<<1025, 256, 0, stream>>>(key, pD, pI, out);
}